// Round 6
// baseline (973.467 us; speedup 1.0000x reference)
//
#include <hip/hip_runtime.h>
#include <math.h>

#define DEPTH 4
#define DMODEL 512
#define DH 64
#define MF 256
#define FFD 2048
#define SEQN 4096
#define NROWS 8192

typedef __bf16 bf16_t;
typedef bf16_t bf16x8 __attribute__((ext_vector_type(8)));
typedef bf16_t bf16x4 __attribute__((ext_vector_type(4)));
typedef float f32x4v __attribute__((ext_vector_type(4)));

static constexpr float DN = 0.35355339059327373f;   // 64^-0.25
static constexpr float RATIO = 0.0625f;             // 256^-0.5
static constexpr float EPSK = 1e-4f;

__device__ __forceinline__ float gelu_exact(float x) {
    return 0.5f * x * (1.0f + erff(x * 0.70710678118654752f));
}

#define AS1(p) ((const __attribute__((address_space(1))) void*)(p))
#define AS3(p) ((__attribute__((address_space(3))) void*)(p))

template <int N> __device__ __forceinline__ void wait_vmcnt() {
    if constexpr (N == 0) asm volatile("s_waitcnt vmcnt(0)" ::: "memory");
    else if constexpr (N == 1) asm volatile("s_waitcnt vmcnt(1)" ::: "memory");
    else if constexpr (N == 2) asm volatile("s_waitcnt vmcnt(2)" ::: "memory");
    else if constexpr (N == 3) asm volatile("s_waitcnt vmcnt(3)" ::: "memory");
    else if constexpr (N == 4) asm volatile("s_waitcnt vmcnt(4)" ::: "memory");
    else if constexpr (N == 5) asm volatile("s_waitcnt vmcnt(5)" ::: "memory");
    else asm volatile("s_waitcnt vmcnt(6)" ::: "memory");
}

// ---------------- LayerNorm -> bf16 ----------------
__global__ __launch_bounds__(256) void ln_kernel(const float* __restrict__ h,
                                                 const float* __restrict__ g,
                                                 const float* __restrict__ b,
                                                 bf16_t* __restrict__ y) {
    int row = blockIdx.x, tid = threadIdx.x;
    const float* hr = h + (size_t)row * DMODEL;
    float v0 = hr[tid], v1 = hr[tid + 256];
    __shared__ float s_sum[256], s_sq[256];
    s_sum[tid] = v0 + v1;
    s_sq[tid] = v0 * v0 + v1 * v1;
    __syncthreads();
    for (int off = 128; off > 0; off >>= 1) {
        if (tid < off) { s_sum[tid] += s_sum[tid + off]; s_sq[tid] += s_sq[tid + off]; }
        __syncthreads();
    }
    float mu = s_sum[0] * (1.0f / DMODEL);
    float var = s_sq[0] * (1.0f / DMODEL) - mu * mu;
    float rstd = rsqrtf(var + 1e-5f);
    bf16_t* yr = y + (size_t)row * DMODEL;
    yr[tid]       = (bf16_t)((v0 - mu) * rstd * g[tid] + b[tid]);
    yr[tid + 256] = (bf16_t)((v1 - mu) * rstd * g[tid + 256] + b[tid + 256]);
}

// ---------------- weight transpose + bf16 convert: Wt[N][K] = (bf16)W[K][N] ----------------
__global__ __launch_bounds__(256) void wconv_kernel(const float* __restrict__ W,
                                                    bf16_t* __restrict__ Wt, int K, int N) {
    __shared__ float t[32][33];
    int n0 = blockIdx.x * 32, k0 = blockIdx.y * 32;
    int tx = threadIdx.x & 31, ty = threadIdx.x >> 5;
#pragma unroll
    for (int i = 0; i < 32; i += 8)
        t[ty + i][tx] = W[(size_t)(k0 + ty + i) * N + n0 + tx];
    __syncthreads();
#pragma unroll
    for (int i = 0; i < 32; i += 8)
        Wt[(size_t)(n0 + ty + i) * K + k0 + tx] = (bf16_t)t[tx][ty + i];
}

// ---------------- proj -> bf16 ----------------
__global__ __launch_bounds__(256) void pconv_kernel(const float* __restrict__ proj,
                                                    bf16_t* __restrict__ projb) {
    int i = (blockIdx.x * 256 + threadIdx.x) * 4;
    float4 v = *(const float4*)(proj + i);
    bf16x4 o;
    o[0] = (bf16_t)v.x; o[1] = (bf16_t)v.y; o[2] = (bf16_t)v.z; o[3] = (bf16_t)v.w;
    *(bf16x4*)(projb + i) = o;
}

// ---------------- Pipelined MFMA GEMM: C[M,N] = act(A[M,K] @ Bt[N,K]^T + bias) ----------------
// P-deep LDS buffers, counted vmcnt (T3+T4), raw s_barrier, one barrier per K-step.
// Uniform L global_load_lds per wave per tile; XOR swizzle f(row)=(row^(row>>2))&SWZ on
// pre-swizzled source + ds_read (rule #21). XCD-aware block remap (T1). setprio on MFMA (T5).
template <int BM, int BN, int BK, int P, int WROWS, int WCOLS,
          int ACT, int RES, int WF, int WB, int QKVE>
__global__ __launch_bounds__(512) void gemm_pipe(const bf16_t* __restrict__ A,
                                                 const bf16_t* __restrict__ Bt,
                                                 const float* __restrict__ bias,
                                                 float* __restrict__ Cf,
                                                 bf16_t* __restrict__ Cb,
                                                 bf16_t* __restrict__ Vt,
                                                 int N, int K) {
    constexpr int MR = BM / WROWS / 16;
    constexpr int NR = BN / WCOLS / 16;
    constexpr int CH = BK / 8;             // 16B chunks per row
    constexpr int SWZ = CH - 1;
    constexpr int KS = BK / 32;
    constexpr int TILE = (BM + BN) * BK;   // bf16 elems per buffer
    constexpr int L = TILE / 8 / 512;      // gloads per thread per tile
    static_assert((TILE / 8) % 512 == 0, "non-uniform load count");
    __shared__ __attribute__((aligned(16))) bf16_t smem[P * TILE];
    int tid = threadIdx.x;
    int wv = tid >> 6, ln = tid & 63;
    // XCD-aware remap (grid size is a multiple of 8 for all instantiations)
    int gx = gridDim.x;
    int lin = blockIdx.y * gx + blockIdx.x;
    int per = (gx * gridDim.y) >> 3;
    int orig = (lin & 7) * per + (lin >> 3);
    int m0 = (orig / gx) * BM, n0 = (orig % gx) * BN;
    int wr = (wv / WCOLS) * (MR * 16), wc = (wv % WCOLS) * (NR * 16);
    int lr = ln & 15, kq8 = ln >> 4;
    int nsteps = K / BK;

    auto stage = [&](int tile, int sb) {
        int k0 = tile * BK;
        bf16_t* dst = smem + sb * TILE;
#pragma unroll
        for (int i = 0; i < L; i++) {
            int c = i * 512 + tid;
            int cb = i * 512 + (tid & ~63);        // wave-uniform base chunk
            bool inA = (c < BM * CH);
            int cc = inA ? c : c - BM * CH;
            int row = cc / CH, ch = cc % CH;
            const bf16_t* mat = inA ? A : Bt;
            int r0 = inA ? m0 : n0;
            int chs = ch ^ ((row ^ (row >> 2)) & SWZ);
            const bf16_t* src = mat + (size_t)(r0 + row) * K + k0 + chs * 8;
            __builtin_amdgcn_global_load_lds(AS1(src), AS3(dst + (size_t)cb * 8), 16, 0, 0);
        }
    };

    f32x4v acc[MR][NR] = {};
#pragma unroll
    for (int p = 0; p < P - 1; ++p) stage(p, p);

    int cur = 0;
    for (int t = 0; t < nsteps; ++t) {
        int rem = nsteps - 1 - t;
        if (rem >= P - 2) wait_vmcnt<(P - 2) * L>();
        else if constexpr (P >= 4) {
            if (rem == 1) wait_vmcnt<L>(); else wait_vmcnt<0>();
        } else wait_vmcnt<0>();
        __builtin_amdgcn_s_barrier();
        asm volatile("" ::: "memory");
        if (t + P - 1 < nsteps) stage(t + P - 1, cur == 0 ? P - 1 : cur - 1);
        const bf16_t* base = smem + cur * TILE;
        const bf16_t* bbase = base + BM * BK;
#pragma unroll
        for (int ku = 0; ku < KS; ku++) {
            bf16x8 af[MR], bfr[NR];
#pragma unroll
            for (int m = 0; m < MR; m++) {
                int row = wr + m * 16 + lr;
                int g = ku * 4 + kq8;
                af[m] = *(const bf16x8*)&base[(row * CH + (g ^ ((row ^ (row >> 2)) & SWZ))) * 8];
            }
#pragma unroll
            for (int n = 0; n < NR; n++) {
                int row = wc + n * 16 + lr;
                int g = ku * 4 + kq8;
                bfr[n] = *(const bf16x8*)&bbase[(row * CH + (g ^ ((row ^ (row >> 2)) & SWZ))) * 8];
            }
            __builtin_amdgcn_s_setprio(1);
#pragma unroll
            for (int m = 0; m < MR; m++)
#pragma unroll
                for (int n = 0; n < NR; n++)
                    acc[m][n] = __builtin_amdgcn_mfma_f32_16x16x32_bf16(af[m], bfr[n], acc[m][n], 0, 0, 0);
            __builtin_amdgcn_s_setprio(0);
        }
        cur = (cur + 1 == P) ? 0 : cur + 1;
    }
    int rq = (ln >> 4) * 4;
#pragma unroll
    for (int n = 0; n < NR; n++) {
        int col = n0 + wc + n * 16 + lr;
        float bcol = bias[col];
#pragma unroll
        for (int m = 0; m < MR; m++) {
#pragma unroll
            for (int r = 0; r < 4; r++) {
                int row = m0 + wr + m * 16 + rq + r;
                float v = acc[m][n][r] + bcol;
                if (ACT == 1) v = gelu_exact(v);
                if (QKVE) {
                    int bb = row >> 12, nn = row & 4095;
                    if (col < 1024) {
                        Cb[(size_t)row * 1024 + col] = (bf16_t)v;
                    } else {
                        int hh2 = (col >> 6) & 7, dd2 = col & 63;
                        Vt[(((size_t)bb * 8 + hh2) * 64 + dd2) * 4096 + nn] = (bf16_t)v;
                    }
                } else {
                    size_t idx = (size_t)row * N + col;
                    if (RES) Cf[idx] += v;
                    else if (WF) Cf[idx] = v;
                    if (WB) Cb[idx] = (bf16_t)v;
                }
            }
        }
    }
}

// ---------------- FAVOR+ feature GEMM: dd[128n x 256m] per block, K=64 ----------------
// MODE 0 = Q (rowmax+exp -> QP[bh][n][m] bf16)
// MODE 1 = K max pass (block max of dd -> kpart)
// MODE 2 = K write pass (exp with kmx -> KPt[bh][m][n] bf16, transposed)
template <int MODE>
__global__ __launch_bounds__(256) void feat_kernel(const bf16_t* __restrict__ qkvb,
                                                   const bf16_t* __restrict__ projb,
                                                   const float* __restrict__ kmaxb,
                                                   bf16_t* __restrict__ outp,
                                                   float* __restrict__ kpart) {
    int bid = blockIdx.x;
    int bh = bid >> 5, tile = bid & 31;
    int b = bh >> 3, hh = bh & 7;
    int tid = threadIdx.x, wv = tid >> 6, ln = tid & 63;
    __shared__ __attribute__((aligned(16))) bf16_t As[128 * 64];
    __shared__ __attribute__((aligned(16))) bf16_t Bs[256 * 64];
    __shared__ float diag_s[128];
    __shared__ float rmx_s[2][128];
    __shared__ float red_s[256];
    int n0 = tile * 128;
    int qoff = (MODE == 0 ? 0 : 512) + hh * 64;
    int lrow8 = ln >> 3;
    int lchunk = ((ln & 7) ^ (lrow8 & 7)) * 8;   // pre-swizzled source chunk
#pragma unroll
    for (int i = 0; i < 4; i++) {
        int e = wv * 4 + i;
        size_t src = (size_t)(b * SEQN + n0 + e * 8 + lrow8) * 1024 + qoff + lchunk;
        __builtin_amdgcn_global_load_lds(AS1(qkvb + src), AS3(&As[e * 512]), 16, 0, 0);
    }
#pragma unroll
    for (int i = 0; i < 8; i++) {
        int e = wv * 8 + i;
        size_t src = (size_t)(e * 8 + lrow8) * 64 + lchunk;
        __builtin_amdgcn_global_load_lds(AS1(projb + src), AS3(&Bs[e * 512]), 16, 0, 0);
    }
    __syncthreads();
    if (MODE != 1 && tid < 128) {
        float s = 0.f;
#pragma unroll
        for (int c = 0; c < 8; c++) {
            bf16x8 v = *(const bf16x8*)&As[tid * 64 + ((c ^ (tid & 7)) * 8)];
#pragma unroll
            for (int j = 0; j < 8; j++) { float f = (float)v[j]; s += f * f; }
        }
        diag_s[tid] = s * (0.5f * DN * DN);
    }
    int wr = (wv >> 1) * 64, wc = (wv & 1) * 128;
    int lr = ln & 15, kg = ln >> 4, rq = kg * 4;
    f32x4v acc[4][8] = {};
#pragma unroll
    for (int ks = 0; ks < 2; ks++) {
        int g = ks * 4 + kg;
        bf16x8 af[4], bfv[8];
#pragma unroll
        for (int m = 0; m < 4; m++) {
            int row = wr + m * 16 + lr;
            af[m] = *(const bf16x8*)&As[row * 64 + ((g ^ (row & 7)) * 8)];
        }
#pragma unroll
        for (int n = 0; n < 8; n++) {
            int row = wc + n * 16 + lr;
            bfv[n] = *(const bf16x8*)&Bs[row * 64 + ((g ^ (row & 7)) * 8)];
        }
#pragma unroll
        for (int m = 0; m < 4; m++)
#pragma unroll
            for (int n = 0; n < 8; n++)
                acc[m][n] = __builtin_amdgcn_mfma_f32_16x16x32_bf16(af[m], bfv[n], acc[m][n], 0, 0, 0);
    }
    if (MODE == 1) {
        float mx = -1e30f;
#pragma unroll
        for (int m = 0; m < 4; m++)
#pragma unroll
            for (int n = 0; n < 8; n++)
#pragma unroll
                for (int r = 0; r < 4; r++) mx = fmaxf(mx, acc[m][n][r]);
        red_s[tid] = mx * DN;
        __syncthreads();
        for (int off = 128; off > 0; off >>= 1) {
            if (tid < off) red_s[tid] = fmaxf(red_s[tid], red_s[tid + off]);
            __syncthreads();
        }
        if (tid == 0) kpart[bid] = red_s[0];
    } else if (MODE == 2) {
        float kmx = kmaxb[bh];
        __syncthreads();   // diag_s visible
#pragma unroll
        for (int m = 0; m < 4; m++) {
#pragma unroll
            for (int n = 0; n < 8; n++) {
                int col = wc + n * 16 + lr;
                bf16x4 pk;
#pragma unroll
                for (int r = 0; r < 4; r++) {
                    int row = wr + m * 16 + rq + r;
                    pk[r] = (bf16_t)(RATIO * (expf(acc[m][n][r] * DN - diag_s[row] - kmx) + EPSK));
                }
                *(bf16x4*)&outp[((size_t)bh * MF + col) * 4096 + n0 + wr + m * 16 + rq] = pk;
            }
        }
    } else {
        float pmax[4][4];
#pragma unroll
        for (int m = 0; m < 4; m++)
#pragma unroll
            for (int r = 0; r < 4; r++) {
                float mx = acc[m][0][r];
#pragma unroll
                for (int n = 1; n < 8; n++) mx = fmaxf(mx, acc[m][n][r]);
#pragma unroll
                for (int mask = 1; mask < 16; mask <<= 1)
                    mx = fmaxf(mx, __shfl_xor(mx, mask));
                pmax[m][r] = mx;
            }
        if (lr == 0) {
#pragma unroll
            for (int m = 0; m < 4; m++)
#pragma unroll
                for (int r = 0; r < 4; r++)
                    rmx_s[wv & 1][wr + m * 16 + rq + r] = pmax[m][r] * DN;
        }
        __syncthreads();
#pragma unroll
        for (int m = 0; m < 4; m++) {
#pragma unroll
            for (int r = 0; r < 4; r++) {
                int row = wr + m * 16 + rq + r;
                float rm = fmaxf(rmx_s[0][row], rmx_s[1][row]);
                float dg = diag_s[row];
                size_t obase = ((size_t)bh * SEQN + n0 + row) * MF;
#pragma unroll
                for (int n = 0; n < 8; n++) {
                    float val = RATIO * (expf(acc[m][n][r] * DN - dg - rm) + EPSK);
                    outp[obase + wc + n * 16 + lr] = (bf16_t)val;
                }
            }
        }
    }
}

__global__ __launch_bounds__(64) void kmax_reduce_kernel(const float* __restrict__ part,
                                                         float* __restrict__ kmax) {
    int bh = blockIdx.x, tid = threadIdx.x;
    float v = (tid < 32) ? part[bh * 32 + tid] : -1e30f;
#pragma unroll
    for (int off = 16; off > 0; off >>= 1) v = fmaxf(v, __shfl_down(v, off));
    if (tid == 0) kmax[bh] = v;
}

// ---------------- ksum: row sums of KPt ----------------
__global__ __launch_bounds__(256) void ksum_kernel(const bf16_t* __restrict__ KPt,
                                                   float* __restrict__ ksum) {
    int row = blockIdx.x, tid = threadIdx.x;
    const bf16_t* r = KPt + (size_t)row * 4096;
    float s = 0.f;
#pragma unroll
    for (int i = 0; i < 2; i++) {
        bf16x8 v = *(const bf16x8*)&r[tid * 16 + i * 8];
#pragma unroll
        for (int j = 0; j < 8; j++) s += (float)v[j];
    }
    __shared__ float red[256];
    red[tid] = s; __syncthreads();
    for (int off = 128; off > 0; off >>= 1) {
        if (tid < off) red[tid] += red[tid + off];
        __syncthreads();
    }
    if (tid == 0) ksum[row] = red[0];
}

// ---------------- ctx split-K GEMM: part[kc][bh][m][d] = KPt-chunk @ Vt-chunk^T ----------------
__global__ __launch_bounds__(256) void ctx_gemm(const bf16_t* __restrict__ KPt,
                                                const bf16_t* __restrict__ Vt,
                                                float* __restrict__ part) {
    int bh = blockIdx.y;
    int mtile = blockIdx.x & 1, kc = blockIdx.x >> 1;
    int m0 = mtile * 128, nb = kc * 512;
    int tid = threadIdx.x, wv = tid >> 6, ln = tid & 63;
    __shared__ __attribute__((aligned(16))) bf16_t As[128 * 64];
    __shared__ __attribute__((aligned(16))) bf16_t Bs[64 * 64];
    int lrow8 = ln >> 3;
    int lchunk = ((ln & 7) ^ (lrow8 & 7)) * 8;
    int lr = ln & 15, kg = ln >> 4, rq = kg * 4;
    int wr = wv * 32;
    f32x4v acc[2][4] = {};
    for (int kt = 0; kt < 8; kt++) {
        int noff = nb + kt * 64;
        __syncthreads();
#pragma unroll
        for (int i = 0; i < 4; i++) {
            int e = wv * 4 + i;
            __builtin_amdgcn_global_load_lds(
                AS1(KPt + ((size_t)bh * MF + m0 + e * 8 + lrow8) * 4096 + noff + lchunk),
                AS3(&As[e * 512]), 16, 0, 0);
        }
#pragma unroll
        for (int i = 0; i < 2; i++) {
            int e = wv * 2 + i;
            __builtin_amdgcn_global_load_lds(
                AS1(Vt + ((size_t)bh * 64 + e * 8 + lrow8) * 4096 + noff + lchunk),
                AS3(&Bs[e * 512]), 16, 0, 0);
        }
        __syncthreads();
#pragma unroll
        for (int ks = 0; ks < 2; ks++) {
            int g = ks * 4 + kg;
            bf16x8 af[2], bfv[4];
#pragma unroll
            for (int m = 0; m < 2; m++) {
                int row = wr + m * 16 + lr;
                af[m] = *(const bf16x8*)&As[row * 64 + ((g ^ (row & 7)) * 8)];
            }
#pragma unroll
            for (int n = 0; n < 4; n++) {
                int row = n * 16 + lr;
                bfv[n] = *(const bf16x8*)&Bs[row * 64 + ((g ^ (row & 7)) * 8)];
            }
#pragma unroll
            for (int m = 0; m < 2; m++)
#pragma unroll
                for (int n = 0; n < 4; n++)
                    acc[m][n] = __builtin_amdgcn_mfma_f32_16x16x32_bf16(af[m], bfv[n], acc[m][n], 0, 0, 0);
        }
    }
#pragma unroll
    for (int m = 0; m < 2; m++)
#pragma unroll
        for (int n = 0; n < 4; n++)
#pragma unroll
            for (int r = 0; r < 4; r++)
                part[((size_t)(kc * 16 + bh) * MF + m0 + wr + m * 16 + rq + r) * 64 + n * 16 + lr] =
                    acc[m][n][r];
}

// ---------------- ctx reduce (8 partials) -> ctx_t[bh][d][m] bf16 ----------------
__global__ __launch_bounds__(256) void ctx_reduce_kernel(const float* __restrict__ part,
                                                         bf16_t* __restrict__ ctx_t) {
    int bh = blockIdx.x;
    for (int it = 0; it < 64; it++) {
        int idx = it * 256 + threadIdx.x;
        int m = idx >> 6, d = idx & 63;
        float s = 0.f;
#pragma unroll
        for (int kc = 0; kc < 8; kc++)
            s += part[(size_t)(kc * 16 + bh) * 16384 + idx];
        ctx_t[((size_t)bh * 64 + d) * MF + m] = (bf16_t)s;
    }
}

// ---------------- dinv[bh][n] = 1 / (QP[n,:] . ksum[bh,:]) ----------------
__global__ __launch_bounds__(256) void dinv_kernel(const bf16_t* __restrict__ QP,
                                                   const float* __restrict__ ksum,
                                                   float* __restrict__ dinv) {
    int bid = blockIdx.x, tid = threadIdx.x;
    int bh = bid >> 4;
    __shared__ float ks[256];
    ks[tid] = ksum[bh * MF + tid];
    __syncthreads();
    size_t row = (size_t)bid * 256 + tid;
    const bf16_t* q = QP + row * MF;
    float s = 0.f;
#pragma unroll
    for (int i = 0; i < 32; i++) {
        bf16x8 v = *(const bf16x8*)&q[i * 8];
#pragma unroll
        for (int j = 0; j < 8; j++) s += (float)v[j] * ks[i * 8 + j];
    }
    dinv[row] = 1.0f / s;
}

// ---------------- out GEMM: abuf[n][h*64+d] = (QP @ ctx_t^T)[n][d] * dinv[n] ----------------
__global__ __launch_bounds__(256) void out_gemm(const bf16_t* __restrict__ QP,
                                                const bf16_t* __restrict__ ctx_t,
                                                const float* __restrict__ dinv,
                                                bf16_t* __restrict__ abuf) {
    int bh = blockIdx.y, ntile = blockIdx.x;
    int b = bh >> 3, hh = bh & 7;
    int n0 = ntile * 128;
    int tid = threadIdx.x, wv = tid >> 6, ln = tid & 63;
    __shared__ __attribute__((aligned(16))) bf16_t As[128 * 64];
    __shared__ __attribute__((aligned(16))) bf16_t Bs[64 * 64];
    int lrow8 = ln >> 3;
    int lchunk = ((ln & 7) ^ (lrow8 & 7)) * 8;
    int lr = ln & 15, kg = ln >> 4, rq = kg * 4;
    int wr = wv * 32;
    f32x4v acc[2][4] = {};
    for (int kt = 0; kt < 4; kt++) {
        int koff = kt * 64;
        __syncthreads();
#pragma unroll
        for (int i = 0; i < 4; i++) {
            int e = wv * 4 + i;
            __builtin_amdgcn_global_load_lds(
                AS1(QP + ((size_t)bh * SEQN + n0 + e * 8 + lrow8) * MF + koff + lchunk),
                AS3(&As[e * 512]), 16, 0, 0);
        }
#pragma unroll
        for (int i = 0; i < 2; i++) {
            int e = wv * 2 + i;
            __builtin_amdgcn_global_load_lds(
                AS1(ctx_t + ((size_t)bh * 64 + e * 8 + lrow8) * MF + koff + lchunk),
                AS3(&Bs[e * 512]), 16, 0, 0);
        }
        __syncthreads();
#pragma unroll
        for (int ks = 0; ks < 2; ks++) {
            int g = ks * 4 + kg;
            bf16x8 af[2], bfv[4];
#pragma unroll
            for (int m = 0; m < 2; m++) {
                int row = wr + m * 16 + lr;
                af[m] = *(const bf16x8*)&As[row * 64 + ((g ^ (row & 7)) * 8)];
            }
#pragma unroll
            for (int n = 0; n < 4; n++) {
                int row = n * 16 + lr;
                bfv[n] = *(const bf16x8*)&Bs[row * 64 + ((g ^ (row & 7)) * 8)];
            }
#pragma unroll
            for (int m = 0; m < 2; m++)
#pragma unroll
                for (int n = 0; n < 4; n++)
                    acc[m][n] = __builtin_amdgcn_mfma_f32_16x16x32_bf16(af[m], bfv[n], acc[m][n], 0, 0, 0);
        }
    }
#pragma unroll
    for (int m = 0; m < 2; m++) {
#pragma unroll
        for (int r = 0; r < 4; r++) {
            int row = n0 + wr + m * 16 + rq + r;
            float di = dinv[(size_t)bh * SEQN + row];
#pragma unroll
            for (int n = 0; n < 4; n++)
                abuf[((size_t)b * SEQN + row) * DMODEL + hh * 64 + n * 16 + lr] =
                    (bf16_t)(acc[m][n][r] * di);
        }
    }
}

extern "C" void kernel_launch(void* const* d_in, const int* in_sizes, int n_in,
                              void* d_out, int out_size, void* d_ws, size_t ws_size,
                              hipStream_t stream) {
    const float* x     = (const float*)d_in[0];
    const float* proj  = (const float*)d_in[1];
    const float* ln1_g = (const float*)d_in[2];
    const float* ln1_b = (const float*)d_in[3];
    const float* Wqkv  = (const float*)d_in[4];
    const float* bqkv  = (const float*)d_in[5];
    const float* Wo    = (const float*)d_in[6];
    const float* bo    = (const float*)d_in[7];
    const float* ln2_g = (const float*)d_in[8];
    const float* ln2_b = (const float*)d_in[9];
    const float* Wff1  = (const float*)d_in[10];
    const float* bff1  = (const float*)d_in[11];
    const float* Wff2  = (const float*)d_in[12];
    const float* bff2  = (const float*)d_in[13];

    float* h = (float*)d_out;
    char* ws = (char*)d_ws;
    // Region 0: KPt (32Mi). ybf aliases its first 8Mi (dead before KPt written; ln2 after ctx).
    bf16_t* KPt   = (bf16_t*)(ws);
    bf16_t* ybf   = (bf16_t*)(ws);
    // Region 1: qkvb Q+K [8192][1024] (16Mi). abuf aliases [0,8Mi); ctx_part aliases [8Mi,16Mi).
    bf16_t* qkvb  = (bf16_t*)(ws + 33554432);
    bf16_t* abufb = (bf16_t*)(ws + 33554432);
    float*  ctx_part = (float*)(ws + 33554432 + 8388608);
    // Region 2: QP (32Mi). ffmid aliases (dead after out_gemm/dinv).
    bf16_t* QP    = (bf16_t*)(ws + 50331648);
    bf16_t* ffmidb= (bf16_t*)(ws + 50331648);
    // Region 3: Vt (8Mi)
    bf16_t* Vt    = (bf16_t*)(ws + 83886080);
    // Region 4: weights + small
    bf16_t* wq_t  = (bf16_t*)(ws + 92274688);   // 1536*512*2
    bf16_t* wo_t  = (bf16_t*)(ws + 93847552);   // 512*512*2
    bf16_t* w1_t  = (bf16_t*)(ws + 94371840);   // 2048*512*2
    bf16_t* w2_t  = (bf16_t*)(ws + 96468992);   // 512*2048*2
    bf16_t* projb = (bf16_t*)(ws + 98566144);   // 4*256*64*2
    bf16_t* ctx_t = (bf16_t*)(ws + 98697216);   // 16*64*256*2
    float*  ksumb = (float*)(ws + 99221504);    // 4096*4
    float*  dinvb = (float*)(ws + 99237888);    // 65536*4
    float*  kpart = (float*)(ws + 99500032);    // 512*4
    float*  kmaxb = (float*)(ws + 99502080);    // 16*4

    hipMemcpyAsync(h, x, (size_t)NROWS * DMODEL * sizeof(float),
                   hipMemcpyDeviceToDevice, stream);
    pconv_kernel<<<64, 256, 0, stream>>>(proj, projb);

    for (int i = 0; i < DEPTH; i++) {
        const bf16_t* pj = projb + (size_t)i * MF * DH;
        wconv_kernel<<<dim3(1536 / 32, 512 / 32), 256, 0, stream>>>(
            Wqkv + (size_t)i * DMODEL * 1536, wq_t, 512, 1536);
        wconv_kernel<<<dim3(512 / 32, 512 / 32), 256, 0, stream>>>(
            Wo + (size_t)i * DMODEL * DMODEL, wo_t, 512, 512);
        wconv_kernel<<<dim3(2048 / 32, 512 / 32), 256, 0, stream>>>(
            Wff1 + (size_t)i * DMODEL * FFD, w1_t, 512, 2048);
        wconv_kernel<<<dim3(512 / 32, 2048 / 32), 256, 0, stream>>>(
            Wff2 + (size_t)i * FFD * DMODEL, w2_t, 2048, 512);

        ln_kernel<<<NROWS, 256, 0, stream>>>(h, ln1_g + i * DMODEL, ln1_b + i * DMODEL, ybf);
        gemm_pipe<128, 128, 32, 4, 2, 4, 0, 0, 0, 0, 1>
            <<<dim3(1536 / 128, NROWS / 128), 512, 0, stream>>>(
            ybf, wq_t, bqkv + i * 1536, nullptr, qkvb, Vt, 1536, 512);
        feat_kernel<1><<<512, 256, 0, stream>>>(qkvb, pj, nullptr, nullptr, kpart);
        kmax_reduce_kernel<<<16, 64, 0, stream>>>(kpart, kmaxb);
        feat_kernel<2><<<512, 256, 0, stream>>>(qkvb, pj, kmaxb, KPt, nullptr);
        ksum_kernel<<<4096, 256, 0, stream>>>(KPt, ksumb);
        feat_kernel<0><<<512, 256, 0, stream>>>(qkvb, pj, nullptr, QP, nullptr);
        ctx_gemm<<<dim3(16, 16), 256, 0, stream>>>(KPt, Vt, ctx_part);
        ctx_reduce_kernel<<<16, 256, 0, stream>>>(ctx_part, ctx_t);
        dinv_kernel<<<256, 256, 0, stream>>>(QP, ksumb, dinvb);
        out_gemm<<<dim3(32, 16), 256, 0, stream>>>(QP, ctx_t, dinvb, abufb);
        gemm_pipe<128, 64, 64, 3, 4, 2, 0, 1, 1, 0, 0>
            <<<dim3(512 / 64, NROWS / 128), 512, 0, stream>>>(
            abufb, wo_t, bo + i * DMODEL, h, nullptr, nullptr, 512, 512);

        ln_kernel<<<NROWS, 256, 0, stream>>>(h, ln2_g + i * DMODEL, ln2_b + i * DMODEL, ybf);
        gemm_pipe<128, 128, 32, 4, 2, 4, 1, 0, 0, 1, 0>
            <<<dim3(2048 / 128, NROWS / 128), 512, 0, stream>>>(
            ybf, w1_t, bff1 + i * FFD, nullptr, ffmidb, nullptr, 2048, 512);
        gemm_pipe<128, 64, 64, 3, 4, 2, 0, 1, 1, 0, 0>
            <<<dim3(512 / 64, NROWS / 128), 512, 0, stream>>>(
            ffmidb, w2_t, bff2 + i * DMODEL, h, nullptr, nullptr, 512, 2048);
    }
}